// Round 4
// baseline (4821.620 us; speedup 1.0000x reference)
//
#include <hip/hip_runtime.h>
#include <stdint.h>

#define SS 64
#define BB 64
#define TT 100
#define HOPC 256
#define NFC 256
#define GCC 256
#define ICC 512
#define NC (1.0f/127.0f)
#define CH 2          // chains per block
#define NBLK (64/CH)  // 32 blocks
#define NTHR 512      // 8 waves: lane = (row, g), row=tid>>3, g=tid&7

// f16 weight arena offsets (in halves; same order as inputs 6..19)
#define OFF_FW     0
#define OFF_FWGLU  8192
#define OFF_G1IH   12288
#define OFF_G1HH   36864
#define OFF_GLU1   49152
#define OFF_G2IH   53248
#define OFF_G2HH   77824
#define OFF_GLU2   90112
#define OFF_G3IH   94208
#define OFF_G3HH   118784
#define OFF_GLU3   131072
#define OFF_SKIPD  135168
#define OFF_SKIPG  176128
#define OFF_OUT    192512
#define W_TOTAL    200704
#define XALL_F32   (TT * BB * HOPC)   // 1,638,400 floats

typedef _Float16 f16;
typedef _Float16 h2 __attribute__((ext_vector_type(2)));
union U16 { uint4 u; h2 h[4]; };

#if __has_builtin(__builtin_amdgcn_fdot2)
#define FDOT2(a, b, c) __builtin_amdgcn_fdot2((a), (b), (c), false)
#else
#define FDOT2(a, b, c) ((c) + (float)(a)[0] * (float)(b)[0] + (float)(a)[1] * (float)(b)[1])
#endif

// ---------------- threefry2x32 core (Random123-KAT verified) ----------------
__device__ __forceinline__ uint32_t rotl32(uint32_t x, int r) {
    return (x << r) | (x >> (32 - r));
}

__device__ __forceinline__ void tf2x32(uint32_t k0, uint32_t k1, uint32_t c0, uint32_t c1,
                                       uint32_t& o0, uint32_t& o1) {
    uint32_t k2 = k0 ^ k1 ^ 0x1BD11BDAu;
    uint32_t x0 = c0 + k0, x1 = c1 + k1;
    x0 += x1; x1 = rotl32(x1, 13); x1 ^= x0;
    x0 += x1; x1 = rotl32(x1, 15); x1 ^= x0;
    x0 += x1; x1 = rotl32(x1, 26); x1 ^= x0;
    x0 += x1; x1 = rotl32(x1, 6);  x1 ^= x0;
    x0 += k1; x1 += k2 + 1u;
    x0 += x1; x1 = rotl32(x1, 17); x1 ^= x0;
    x0 += x1; x1 = rotl32(x1, 29); x1 ^= x0;
    x0 += x1; x1 = rotl32(x1, 16); x1 ^= x0;
    x0 += x1; x1 = rotl32(x1, 24); x1 ^= x0;
    x0 += k2; x1 += k0 + 2u;
    x0 += x1; x1 = rotl32(x1, 13); x1 ^= x0;
    x0 += x1; x1 = rotl32(x1, 15); x1 ^= x0;
    x0 += x1; x1 = rotl32(x1, 26); x1 ^= x0;
    x0 += x1; x1 = rotl32(x1, 6);  x1 ^= x0;
    x0 += k0; x1 += k1 + 3u;
    x0 += x1; x1 = rotl32(x1, 17); x1 ^= x0;
    x0 += x1; x1 = rotl32(x1, 29); x1 ^= x0;
    x0 += x1; x1 = rotl32(x1, 16); x1 ^= x0;
    x0 += x1; x1 = rotl32(x1, 24); x1 ^= x0;
    x0 += k1; x1 += k2 + 4u;
    x0 += x1; x1 = rotl32(x1, 13); x1 ^= x0;
    x0 += x1; x1 = rotl32(x1, 15); x1 ^= x0;
    x0 += x1; x1 = rotl32(x1, 26); x1 ^= x0;
    x0 += x1; x1 = rotl32(x1, 6);  x1 ^= x0;
    x0 += k2; x1 += k0 + 5u;
    o0 = x0; o1 = x1;
}

// jax_threefry_partitionable semantics: bits(m) = x0^x1 of block (0, m)
__device__ __forceinline__ float unifP(uint32_t k0, uint32_t k1, uint32_t m) {
    uint32_t o0, o1;
    tf2x32(k0, k1, 0u, m, o0, o1);
    uint32_t bits = o0 ^ o1;
    return __uint_as_float((bits >> 9) | 0x3f800000u) - 1.0f;
}

__device__ __forceinline__ float clipf(float v) { return fminf(1.0f, fmaxf(-1.0f, v)); }
__device__ __forceinline__ float noiseu(float v, float u) {
    return clipf(v + (u - 0.5f) * NC);
}
__device__ __forceinline__ float sigmf(float v) {
    return __fdividef(1.0f, 1.0f + __expf(-v));
}
__device__ __forceinline__ float tanhfast(float x) {
    float ax = fminf(fabsf(x), 15.0f);
    float e = __expf(2.0f * ax);
    float r = __fdividef(e - 1.0f, e + 1.0f);
    return copysignf(r, x);
}

// barrier WITHOUT the vmcnt(0) drain __syncthreads() would emit.
__device__ __forceinline__ void bar_lds() {
    asm volatile("s_waitcnt lgkmcnt(0)\n\ts_barrier" ::: "memory");
}

// ---------------- DPP 8-lane reduction (VALU-only, no DS pipe) --------------
__device__ __forceinline__ float red8dpp(float v) {
    int t;
    t = __builtin_amdgcn_update_dpp(0, __float_as_int(v), 0xB1, 0xF, 0xF, true);  // quad xor1
    v += __int_as_float(t);
    t = __builtin_amdgcn_update_dpp(0, __float_as_int(v), 0x4E, 0xF, 0xF, true);  // quad xor2
    v += __int_as_float(t);
    t = __builtin_amdgcn_update_dpp(0, __float_as_int(v), 0x141, 0xF, 0xF, true); // half-row mirror
    v += __int_as_float(t);
    return v;   // all 8 lanes of the group hold the sum
}

// ---------------- f16 dot helper ----------------
__device__ __forceinline__ float dotU(const U16& w, const U16& x, float acc) {
#pragma unroll
    for (int i = 0; i < 4; ++i) acc = FDOT2(w.h[i], x.h[i], acc);
    return acc;
}

// ---------------- register weight structs + loaders ----------------
struct WF1  { U16 w[2]; };                        // K=128, NR=1
struct WGRU { U16 wih[6]; U16 whh[3]; U16 glu; }; // 40 VGPRs
struct WSK  { U16 w[10]; };                       // K=320, NR=2
struct WSG  { U16 w[4]; };                        // K=128, NR=2

__device__ __forceinline__ void ldF1(const f16* W, int row, int g, WF1& r) {
    const f16* p = W + row * 128 + g * 16;
    r.w[0].u = *(const uint4*)p;
    r.w[1].u = *(const uint4*)(p + 8);
}
__device__ __forceinline__ void ldF2(const f16* W, int row, int g, U16& r) {
    r.u = *(const uint4*)(W + row * 64 + g * 8);
}
__device__ __forceinline__ void ldGRU(const f16* Wih, const f16* Whh, const f16* Glu,
                                      int row, int g, WGRU& r) {
#pragma unroll
    for (int j = 0; j < 3; ++j) {
        const f16* p = Wih + (row + 64 * j) * 128 + g * 16;
        r.wih[2 * j].u     = *(const uint4*)p;
        r.wih[2 * j + 1].u = *(const uint4*)(p + 8);
        r.whh[j].u = *(const uint4*)(Whh + (row + 64 * j) * 64 + g * 8);
    }
    r.glu.u = *(const uint4*)(Glu + row * 64 + g * 8);
}
__device__ __forceinline__ void ldSK(const f16* W, int row, int g, WSK& r) {
#pragma unroll
    for (int j = 0; j < 2; ++j) {
        const f16* p = W + (row + 64 * j) * 320 + g * 40;
#pragma unroll
        for (int i = 0; i < 5; ++i) r.w[5 * j + i].u = *(const uint4*)(p + 8 * i);
    }
}
__device__ __forceinline__ void ldSG(const f16* W, int row, int g, WSG& r) {
#pragma unroll
    for (int j = 0; j < 2; ++j) {
        const f16* p = W + (row + 64 * j) * 128 + g * 16;
        r.w[2 * j].u     = *(const uint4*)p;
        r.w[2 * j + 1].u = *(const uint4*)(p + 8);
    }
}

// opaque pin: makes the loaded values asm-defined -> cannot be rematerialized
__device__ __forceinline__ void pinU(U16& r) {
    asm volatile("" : "+v"(r.u.x), "+v"(r.u.y), "+v"(r.u.z), "+v"(r.u.w));
}

// ---------------- weight convert to f16 (flat, same layout) ----------------
struct SrcW { const float* p[14]; };

__global__ __launch_bounds__(256) void fargan_cvtw(SrcW s, f16* __restrict__ dst) {
    const int offs[15] = {0, 8192, 12288, 36864, 49152, 53248, 77824, 90112,
                          94208, 118784, 131072, 135168, 176128, 192512, 200704};
    int i = blockIdx.x * 256 + threadIdx.x;
    if (i >= W_TOTAL) return;
    int sgi = 0;
#pragma unroll
    for (int t = 1; t < 14; ++t) sgi += (i >= offs[t]);
    dst[i] = (f16)s.p[sgi][i - offs[sgi]];
}

// ---------------- feature transpose: f[b][c][t] -> fT[t][b][c] ----------------
__global__ __launch_bounds__(256) void fargan_tr(const float* __restrict__ f,
                                                 float* __restrict__ fT) {
    __shared__ float L[64][104];
    int b = blockIdx.x >> 2, c0 = (blockIdx.x & 3) * 64;
    for (int e = threadIdx.x; e < 6400; e += 256) {
        int r = e / 100, col = e - r * 100;
        L[r][col] = f[b * NFC * TT + (c0 + r) * TT + col];
    }
    __syncthreads();
    for (int e = threadIdx.x; e < 6400; e += 256) {
        int t = e >> 6, c = e & 63;
        fT[(t * BB + b) * NFC + c0 + c] = L[c][t];
    }
}

// ---------------- frame input network (fp32) ----------------
__global__ __launch_bounds__(256) void fargan_frame(
    const float* __restrict__ fT, const float* __restrict__ gfeat,
    const float* __restrict__ W1, const float* __restrict__ ib1,
    const float* __restrict__ W2, const float* __restrict__ ib2,
    float* __restrict__ xall)
{
    __shared__ __align__(16) float cat[16][ICC];
    __shared__ __align__(16) float zb[16][ICC];
    const int tid = threadIdx.x;
    const int t = blockIdx.x >> 2;
    const int q = blockIdx.x & 3;

    for (int bb = 0; bb < 16; ++bb) {
        int b = q * 16 + bb;
        for (int c = tid; c < ICC; c += 256) {
            float v = (c < NFC) ? fT[(t * BB + b) * NFC + c]
                                : gfeat[b * GCC + (c - NFC)];
            cat[bb][c] = v;
        }
    }
    __syncthreads();

    {
        int rg = tid & 63, bg = tid >> 6;
        int n0 = rg * 8, bb0 = bg * 4;
        float acc[8][4];
#pragma unroll
        for (int r = 0; r < 8; ++r)
#pragma unroll
            for (int j = 0; j < 4; ++j) acc[r][j] = 0.f;
        for (int k = 0; k < ICC; k += 4) {
            float4 cv[4];
#pragma unroll
            for (int j = 0; j < 4; ++j) cv[j] = *(const float4*)&cat[bb0 + j][k];
#pragma unroll
            for (int r = 0; r < 8; ++r) {
                float4 wv = *(const float4*)&W1[(n0 + r) * ICC + k];
#pragma unroll
                for (int j = 0; j < 4; ++j)
                    acc[r][j] += wv.x * cv[j].x + wv.y * cv[j].y + wv.z * cv[j].z + wv.w * cv[j].w;
            }
        }
#pragma unroll
        for (int r = 0; r < 8; ++r) {
            float bias = ib1[n0 + r];
#pragma unroll
            for (int j = 0; j < 4; ++j)
                zb[bb0 + j][n0 + r] = tanhf(acc[r][j] + bias);
        }
    }
    __syncthreads();

    {
        int rg = tid & 63, bg = tid >> 6;
        int n0 = rg * 4, bb0 = bg * 4;
        float acc[4][4];
#pragma unroll
        for (int r = 0; r < 4; ++r)
#pragma unroll
            for (int j = 0; j < 4; ++j) acc[r][j] = 0.f;
        for (int k = 0; k < ICC; k += 4) {
            float4 cv[4];
#pragma unroll
            for (int j = 0; j < 4; ++j) cv[j] = *(const float4*)&zb[bb0 + j][k];
#pragma unroll
            for (int r = 0; r < 4; ++r) {
                float4 wv = *(const float4*)&W2[(n0 + r) * ICC + k];
#pragma unroll
                for (int j = 0; j < 4; ++j)
                    acc[r][j] += wv.x * cv[j].x + wv.y * cv[j].y + wv.z * cv[j].z + wv.w * cv[j].w;
            }
        }
#pragma unroll
        for (int r = 0; r < 4; ++r) {
            float bias = ib2[n0 + r];
#pragma unroll
            for (int j = 0; j < 4; ++j) {
                int b = q * 16 + bb0 + j;
                xall[(t * BB + b) * HOPC + n0 + r] = acc[r][j] + bias;
            }
        }
    }
}

// ---------------- sequential chain ------------------------------------------
// v5: CH=2 chains per block (32 blocks) to amortize the 11 barrier round
// trips over 2x independent work; amdgpu_waves_per_eu(2,2) grants the full
// 256-reg unified budget (launch_bounds(512) alone left the allocator at 128).
// KK key table shared across chains (chain-independent); 3 noise sites cover
// the 1408 next-step uniforms.
__global__ __attribute__((amdgpu_flat_work_group_size(512, 512),
                          amdgpu_waves_per_eu(2, 2)))
void fargan_seq(
    const float* __restrict__ xall, const f16* __restrict__ wh,
    float* __restrict__ outp)
{
    const int tid = threadIdx.x;
    const int row = tid >> 3;
    const int g = tid & 7;
    const int bg = blockIdx.x;          // chain-group id (CH chains)

    __shared__ __align__(16) f16 XH[CH][128];          // xsub|s3 mirrors
    __shared__ __align__(16) f16 SKXH[CH][320];        // g1|g2|g3|fw|prevN
    __shared__ __align__(16) f16 TWH[CH][64], HNH[CH][64];
    __shared__ __align__(16) f16 SPNH[CH][128], SKVH[CH][128];
    __shared__ __align__(16) f16 HH[2][CH][3][64];     // GRU state f16 (ping-pong)
    __shared__ __align__(16) float Hf[2][CH][3][64];   // GRU state fp32 (ping-pong)
    __shared__ __align__(16) float UNF[2][CH][704];    // uniforms (idx parity)
    __shared__ uint32_t KK[401][20];                   // all fold_in keys, all idx

    // ---- one-time: register weights (pinned)
    WF1 rF1;  ldF1(wh + OFF_FW, row, g, rF1);
    U16 rF2;  ldF2(wh + OFF_FWGLU, row, g, rF2);
    WGRU rG1; ldGRU(wh + OFF_G1IH, wh + OFF_G1HH, wh + OFF_GLU1, row, g, rG1);
    WGRU rG2; ldGRU(wh + OFF_G2IH, wh + OFF_G2HH, wh + OFF_GLU2, row, g, rG2);
    WGRU rG3; ldGRU(wh + OFF_G3IH, wh + OFF_G3HH, wh + OFF_GLU3, row, g, rG3);
    WSG rSG;  ldSG(wh + OFF_SKIPG, row, g, rSG);
    WF1 rOUT; ldF1(wh + OFF_OUT, row, g, rOUT);

    pinU(rF1.w[0]); pinU(rF1.w[1]); pinU(rF2);
#pragma unroll
    for (int j = 0; j < 6; ++j) { pinU(rG1.wih[j]); pinU(rG2.wih[j]); pinU(rG3.wih[j]); }
#pragma unroll
    for (int j = 0; j < 3; ++j) { pinU(rG1.whh[j]); pinU(rG2.whh[j]); pinU(rG3.whh[j]); }
    pinU(rG1.glu); pinU(rG2.glu); pinU(rG3.glu);
#pragma unroll
    for (int j = 0; j < 4; ++j) pinU(rSG.w[j]);
    pinU(rOUT.w[0]); pinU(rOUT.w[1]);

    float prevO[CH], xs_old[CH];
#pragma unroll
    for (int c = 0; c < CH; ++c) { prevO[c] = 0.f; xs_old[c] = 0.f; }

    // ---- init state (CH*64 rows)
    if (tid < CH * 64) {
        int c = tid >> 6, r = tid & 63;
#pragma unroll
        for (int i = 0; i < 3; ++i) { Hf[0][c][i][r] = 0.f; HH[0][c][i][r] = (f16)0.f; }
        XH[c][r] = (f16)0.f; XH[c][64 + r] = (f16)0.f;
    }

    // ---- prologue: ALL keys for ALL idx (401 x 10 pairs), once
    for (int e = tid; e < 4010; e += NTHR) {
        int ii = e / 10, ki = e - ii * 10;
        uint32_t f0, f1; tf2x32(0u, 1u, 0u, (uint32_t)ii, f0, f1);
        uint32_t A, Bv;  tf2x32(f0, f1, 0u, (uint32_t)ki, A, Bv);
        KK[ii][2 * ki] = A; KK[ii][2 * ki + 1] = Bv;
    }
    __syncthreads();

    // ---- prologue: uniforms for idx 0 (CH*704 slots)
    for (int e = tid; e < CH * 704; e += NTHR) {
        int c2 = (e >= 704) ? 1 : 0;
        int j2 = e - 704 * c2;
        int sl = j2 >> 6;
        int kx = (sl < 9) ? 2 * sl : 18;
        uint32_t m2 = (sl < 9) ? (uint32_t)((bg * CH + c2) * 64 + (j2 & 63))
                               : (uint32_t)((bg * CH + c2) * 128 + (j2 - 576));
        UNF[0][c2][j2] = unifP(KK[0][kx], KK[0][kx + 1], m2);
    }

    // ---- prologue: x prefetch for frame 0 (CH x 4 subframes)
    float xfA0 = xall[(0 * BB + bg * CH + 0) * HOPC + 0 * SS + row];
    float xfA1 = xall[(0 * BB + bg * CH + 0) * HOPC + 1 * SS + row];
    float xfA2 = xall[(0 * BB + bg * CH + 0) * HOPC + 2 * SS + row];
    float xfA3 = xall[(0 * BB + bg * CH + 0) * HOPC + 3 * SS + row];
    float xfB0 = xall[(0 * BB + bg * CH + 1) * HOPC + 0 * SS + row];
    float xfB1 = xall[(0 * BB + bg * CH + 1) * HOPC + 1 * SS + row];
    float xfB2 = xall[(0 * BB + bg * CH + 1) * HOPC + 2 * SS + row];
    float xfB3 = xall[(0 * BB + bg * CH + 1) * HOPC + 3 * SS + row];
    __syncthreads();

// one unifP per lane per site for next step; 3 sites x 512 lanes >= CH*704
#define GEN_SITE(SITEI) do {                                                    \
        int id_ = (SITEI) * 512 + tid;                                          \
        if (id_ < CH * 704) {                                                   \
            int c2 = (id_ >= 704) ? 1 : 0;                                      \
            int j2 = id_ - 704 * c2;                                            \
            int sl = j2 >> 6;                                                   \
            int kx = (sl < 9) ? 2 * sl : 18;                                    \
            uint32_t m2 = (sl < 9) ? (uint32_t)((bg * CH + c2) * 64 + (j2 & 63))   \
                                   : (uint32_t)((bg * CH + c2) * 128 + (j2 - 576)); \
            UNF[p ^ 1][c2][j2] = unifP(KK[idx + 1][kx], KK[idx + 1][kx + 1], m2); \
        } } while (0)

    for (int t = 0; t < TT; ++t) {
        // prefetch next frame's x (consumed 4..8 steps from now)
        const int tn = (t + 1 < TT) ? t + 1 : t;
        float xnA0 = xall[(tn * BB + bg * CH + 0) * HOPC + 0 * SS + row];
        float xnA1 = xall[(tn * BB + bg * CH + 0) * HOPC + 1 * SS + row];
        float xnA2 = xall[(tn * BB + bg * CH + 0) * HOPC + 2 * SS + row];
        float xnA3 = xall[(tn * BB + bg * CH + 0) * HOPC + 3 * SS + row];
        float xnB0 = xall[(tn * BB + bg * CH + 1) * HOPC + 0 * SS + row];
        float xnB1 = xall[(tn * BB + bg * CH + 1) * HOPC + 1 * SS + row];
        float xnB2 = xall[(tn * BB + bg * CH + 1) * HOPC + 2 * SS + row];
        float xnB3 = xall[(tn * BB + bg * CH + 1) * HOPC + 3 * SS + row];

        for (int s = 0; s < 4; ++s) {
            const int idx = t * 4 + s;
            const int p = idx & 1;       // parity (H state, UNF)

            // ======== A: input/prev noise                          [barrier 1]
            if (g == 0) {
                float xvA = (s == 0) ? xfA0 : (s == 1) ? xfA1 : (s == 2) ? xfA2 : xfA3;
                float xvB = (s == 0) ? xfB0 : (s == 1) ? xfB1 : (s == 2) ? xfB2 : xfB3;
                float xsA = noiseu(xvA, UNF[p][0][row]);
                float xsB = noiseu(xvB, UNF[p][1][row]);
                XH[0][row] = (f16)xsA; XH[0][64 + row] = (f16)xs_old[0]; xs_old[0] = xsA;
                XH[1][row] = (f16)xsB; XH[1][64 + row] = (f16)xs_old[1]; xs_old[1] = xsB;
                SKXH[0][256 + row] = (f16)noiseu(prevO[0], UNF[p][0][64 + row]);
                SKXH[1][256 + row] = (f16)noiseu(prevO[1], UNF[p][1][64 + row]);
            }
            bar_lds();

            // ======== FW1: tw = tanh(fw_W @ [xsub; s3])            [barrier 2]
            float twv[CH];
            {
                U16 xa[CH], xb[CH];
#pragma unroll
                for (int c = 0; c < CH; ++c) {
                    xa[c].u = *(const uint4*)&XH[c][g * 16];
                    xb[c].u = *(const uint4*)&XH[c][g * 16 + 8];
                }
#pragma unroll
                for (int c = 0; c < CH; ++c) {
                    float a = dotU(rF1.w[0], xa[c], 0.f);
                    a = dotU(rF1.w[1], xb[c], a);
                    twv[c] = tanhfast(red8dpp(a));
                    if (g == 0) TWH[c][row] = (f16)twv[c];
                }
            }
            bar_lds();

            // ======== FW2 + noise site 0                           [barrier 3]
            {
                U16 xa[CH];
#pragma unroll
                for (int c = 0; c < CH; ++c) xa[c].u = *(const uint4*)&TWH[c][g * 8];
                GEN_SITE(0);
#pragma unroll
                for (int c = 0; c < CH; ++c) {
                    float a = red8dpp(dotU(rF2, xa[c], 0.f));
                    if (g == 0) SKXH[c][192 + row] =
                        (f16)noiseu(twv[c] * sigmf(a), UNF[p][c][128 + row]);
                }
            }
            bar_lds();

            // ======== GRU+GLU x3 (2 barriers each)
#define GRU_STEP(RG, XEXPR, GI, UH, UG, GOFF, PRE1, PRE2)                                   \
            {                                                                               \
                float hNv[CH];                                                              \
                U16 xa[CH], xb[CH], xh[CH];                                                 \
                _Pragma("unroll")                                                           \
                for (int c = 0; c < CH; ++c) {                                              \
                    const f16* xin = (XEXPR);                                               \
                    xa[c].u = *(const uint4*)xin;                                           \
                    xb[c].u = *(const uint4*)(xin + 8);                                     \
                    xh[c].u = *(const uint4*)&HH[p][c][GI][g * 8];                          \
                }                                                                           \
                PRE1;                                                                       \
                _Pragma("unroll")                                                           \
                for (int c = 0; c < CH; ++c) {                                              \
                    float ai0 = 0, ai1 = 0, ai2 = 0, ah0 = 0, ah1 = 0, ah2 = 0;             \
                    ai0 = dotU(RG.wih[0], xa[c], ai0); ai0 = dotU(RG.wih[1], xb[c], ai0);   \
                    ai1 = dotU(RG.wih[2], xa[c], ai1); ai1 = dotU(RG.wih[3], xb[c], ai1);   \
                    ai2 = dotU(RG.wih[4], xa[c], ai2); ai2 = dotU(RG.wih[5], xb[c], ai2);   \
                    ah0 = dotU(RG.whh[0], xh[c], ah0);                                      \
                    ah1 = dotU(RG.whh[1], xh[c], ah1);                                      \
                    ah2 = dotU(RG.whh[2], xh[c], ah2);                                      \
                    ai0 = red8dpp(ai0); ai1 = red8dpp(ai1); ai2 = red8dpp(ai2);             \
                    ah0 = red8dpp(ah0); ah1 = red8dpp(ah1); ah2 = red8dpp(ah2);             \
                    float hold = Hf[p][c][GI][row];                                         \
                    float r  = sigmf(ai0 + ah0);                                            \
                    float z  = sigmf(ai1 + ah1);                                            \
                    float nn = tanhfast(ai2 + r * ah2);                                     \
                    float hnew = (1.f - z) * nn + z * hold;                                 \
                    hNv[c] = noiseu(hnew, UNF[p][c][(UH) + row]);                           \
                    if (g == 0) {                                                           \
                        Hf[p ^ 1][c][GI][row] = hnew;                                       \
                        HH[p ^ 1][c][GI][row] = (f16)hnew;                                  \
                        HNH[c][row] = (f16)hNv[c];                                          \
                    }                                                                       \
                }                                                                           \
                bar_lds();                                                                  \
                PRE2;                                                                       \
                _Pragma("unroll")                                                           \
                for (int c = 0; c < CH; ++c) {                                              \
                    U16 xg; xg.u = *(const uint4*)&HNH[c][g * 8];                           \
                    float ag = red8dpp(dotU(RG.glu, xg, 0.f));                              \
                    if (g == 0) SKXH[c][(GOFF) + row] =                                     \
                        (f16)noiseu(hNv[c] * sigmf(ag), UNF[p][c][(UG) + row]);             \
                }                                                                           \
            }                                                                               \
            bar_lds();

            WSK rSK;
            GRU_STEP(rG1, &SKXH[c][192 + g * 16], 0, 192, 256, 0,
                     GEN_SITE(1), (void)0)
            GRU_STEP(rG2, (g < 4 ? &SKXH[c][g * 16] : &SKXH[c][256 + (g - 4) * 16]),
                     1, 320, 384, 64, GEN_SITE(2), (void)0)
            GRU_STEP(rG3, (g < 4 ? &SKXH[c][64 + g * 16] : &SKXH[c][256 + (g - 4) * 16]),
                     2, 448, 512, 128, (void)0,
                     ldSK(wh + OFF_SKIPD, row, g, rSK))   // rSK load in GLU3 half
#undef GRU_STEP

            // ======== SKIP: spN = noise(tanh(skip_dense @ SKXH))   [barrier 10]
            float sp0[CH], sp1[CH];
            {
#pragma unroll
                for (int c = 0; c < CH; ++c) {
                    U16 xs5[5];
#pragma unroll
                    for (int i = 0; i < 5; ++i) xs5[i].u = *(const uint4*)&SKXH[c][g * 40 + 8 * i];
                    float a0 = 0, a1 = 0;
#pragma unroll
                    for (int i = 0; i < 5; ++i) {
                        a0 = dotU(rSK.w[i], xs5[i], a0);
                        a1 = dotU(rSK.w[5 + i], xs5[i], a1);
                    }
                    sp0[c] = noiseu(tanhfast(red8dpp(a0)), UNF[p][c][576 + row]);
                    sp1[c] = noiseu(tanhfast(red8dpp(a1)), UNF[p][c][640 + row]);
                    if (g == 0) { SPNH[c][row] = (f16)sp0[c]; SPNH[c][64 + row] = (f16)sp1[c]; }
                }
            }
            bar_lds();

            // ======== SG: skip = spN * sigm(skip_glu @ spN)        [barrier 11]
            {
#pragma unroll
                for (int c = 0; c < CH; ++c) {
                    U16 xa, xb;
                    xa.u = *(const uint4*)&SPNH[c][g * 16];
                    xb.u = *(const uint4*)&SPNH[c][g * 16 + 8];
                    float a0 = dotU(rSG.w[0], xa, 0.f); a0 = dotU(rSG.w[1], xb, a0);
                    float a1 = dotU(rSG.w[2], xa, 0.f); a1 = dotU(rSG.w[3], xb, a1);
                    a0 = red8dpp(a0); a1 = red8dpp(a1);
                    if (g == 0) {
                        SKVH[c][row]      = (f16)(sp0[c] * sigmf(a0));
                        SKVH[c][64 + row] = (f16)(sp1[c] * sigmf(a1));
                    }
                }
            }
            bar_lds();

            // ======== OUT: o = tanh(out_W @ skip)   [no barrier]
            {
#pragma unroll
                for (int c = 0; c < CH; ++c) {
                    U16 xa, xb;
                    xa.u = *(const uint4*)&SKVH[c][g * 16];
                    xb.u = *(const uint4*)&SKVH[c][g * 16 + 8];
                    float a = dotU(rOUT.w[0], xa, 0.f);
                    a = dotU(rOUT.w[1], xb, a);
                    float o = tanhfast(red8dpp(a));
                    prevO[c] = o;
                    if (g == 0)
                        outp[(bg * CH + c) * (TT * HOPC) + t * HOPC + s * SS + row] = o;
                }
            }
        }
        xfA0 = xnA0; xfA1 = xnA1; xfA2 = xnA2; xfA3 = xnA3;
        xfB0 = xnB0; xfB1 = xnB1; xfB2 = xnB2; xfB3 = xnB3;
    }
#undef GEN_SITE
}

extern "C" void kernel_launch(void* const* d_in, const int* in_sizes, int n_in,
                              void* d_out, int out_size, void* d_ws, size_t ws_size,
                              hipStream_t stream) {
    const float* features = (const float*)d_in[0];
    const float* gfeat    = (const float*)d_in[1];
    const float* W1       = (const float*)d_in[2];
    const float* ib1      = (const float*)d_in[3];
    const float* W2       = (const float*)d_in[4];
    const float* ib2      = (const float*)d_in[5];

    float* xall = (float*)d_ws;                    // 6.55 MB
    float* fT   = xall + XALL_F32;                 // 6.55 MB
    f16*   wh   = (f16*)(fT + XALL_F32);           // 0.40 MB
    float* outp = (float*)d_out;

    SrcW sw;
    for (int i = 0; i < 14; ++i) sw.p[i] = (const float*)d_in[6 + i];

    hipLaunchKernelGGL(fargan_cvtw, dim3((W_TOTAL + 255) / 256), dim3(256), 0, stream, sw, wh);
    hipLaunchKernelGGL(fargan_tr, dim3(256), dim3(256), 0, stream, features, fT);
    hipLaunchKernelGGL(fargan_frame, dim3(TT * 4), dim3(256), 0, stream,
                       fT, gfeat, W1, ib1, W2, ib2, xall);
    hipLaunchKernelGGL(fargan_seq, dim3(NBLK), dim3(NTHR), 0, stream, xall, wh, outp);
}